// Round 7
// baseline (313.789 us; speedup 1.0000x reference)
//
#include <hip/hip_runtime.h>

typedef __attribute__((ext_vector_type(8))) short short8;
typedef __attribute__((ext_vector_type(4))) float floatx4;

#define N_    2
#define LQ_   21760
#define D_    256
#define M_    8
#define L_    4
#define P_    4
#define DH_   32
#define LEN_  21760
#define BQ    16

__constant__ int c_start[4] = {0, 16384, 20480, 21504};
__constant__ int c_HW[4]    = {128, 64, 32, 16};

// ws layout (bytes):
//   vproj bf16 [N*M][LEN_][32] @ 0  (22,282,240 B)
//   wt bf16: Wofft[256][256] @ elem 0, Wattt[128][256] @ 65536,
//            Woutt[256][256] @ 98304, Wvt[256][256] @ 163840
#define WT_BYTE_OFF 22282240u

__device__ __forceinline__ unsigned short f2bf(float f) {
  unsigned int u = __builtin_bit_cast(unsigned int, f);
  u += 0x7fffu + ((u >> 16) & 1u);   // RNE
  return (unsigned short)(u >> 16);
}
__device__ __forceinline__ float bf2f(unsigned short s) {
  return __builtin_bit_cast(float, ((unsigned int)s) << 16);
}

// ---------------- prep: transpose + convert weights to bf16 ----------------
__global__ __launch_bounds__(256) void prep_kernel(
    const float* __restrict__ Woff, const float* __restrict__ Watt,
    const float* __restrict__ Wout, const float* __restrict__ Wv,
    unsigned short* __restrict__ wt) {
  const int b = blockIdx.x, t = threadIdx.x;
  const float* src; int ncols, n; unsigned short* dst;
  if (b < 256)      { src = Woff; ncols = 256; n = b;       dst = wt + 0      + n * 256; }
  else if (b < 384) { src = Watt; ncols = 128; n = b - 256; dst = wt + 65536  + n * 256; }
  else if (b < 640) { src = Wout; ncols = 256; n = b - 384; dst = wt + 98304  + n * 256; }
  else              { src = Wv;   ncols = 256; n = b - 640; dst = wt + 163840 + n * 256; }
  dst[t] = f2bf(src[(size_t)t * ncols + n]);
}

// ---------------- vproj: value @ W_val + b_val -> bf16 [n][m][pix][32] -----
__global__ __launch_bounds__(256, 2) void vproj_kernel(
    const float* __restrict__ value, const unsigned short* __restrict__ Wvt,
    const float* __restrict__ bv, unsigned short* __restrict__ vout) {
  __shared__ unsigned short vs[64][264];
  const int t = threadIdx.x;
  const int r0 = blockIdx.x * 64;
  {
    const int c2 = (t & 127) * 2;
    const int rb = t >> 7;
#pragma unroll
    for (int i = 0; i < 32; ++i) {
      int rr = rb + i * 2;
      float2 v = *(const float2*)(value + (size_t)(r0 + rr) * D_ + c2);
      *(unsigned int*)&vs[rr][c2] = (unsigned int)f2bf(v.x) | ((unsigned int)f2bf(v.y) << 16);
    }
  }
  __syncthreads();
  const int wave = t >> 6, lane = t & 63;
  const int arow = wave * 16 + (lane & 15);
  const int kg = (lane >> 4) * 8;
  floatx4 acc[16] = {};
  for (int kk = 0; kk < 8; ++kk) {
    const int k0 = kk * 32;
    short8 af = *(const short8*)&vs[arow][k0 + kg];
#pragma unroll
    for (int ct = 0; ct < 16; ++ct) {
      const int col = ct * 16 + (lane & 15);
      short8 bf = *(const short8*)(Wvt + col * 256 + k0 + kg);
      acc[ct] = __builtin_amdgcn_mfma_f32_16x16x32_bf16(af, bf, acc[ct], 0, 0, 0);
    }
  }
  const int n = (r0 >= LEN_) ? 1 : 0;
  const int pixbase = r0 - n * LEN_ + wave * 16 + ((lane >> 4) * 4);
#pragma unroll
  for (int ct = 0; ct < 16; ++ct) {
    const int gc = ct * 16 + (lane & 15);
    const int m = gc >> 5, d = gc & 31;
    const float bb = bv[gc];
    unsigned short* ob = vout + ((size_t)(n * M_ + m) * LEN_) * DH_ + d;
#pragma unroll
    for (int j = 0; j < 4; ++j)
      ob[(size_t)(pixbase + j) * DH_] = f2bf(acc[ct][j] + bb);
  }
}

// ---------------- msda: fused proj/softmax/sample/out ----------------------
__global__ __launch_bounds__(256, 4) void msda_kernel(
    const float* __restrict__ query, const float* __restrict__ refp,
    const unsigned short* __restrict__ wt,
    const float* __restrict__ boff, const float* __restrict__ batt,
    const float* __restrict__ bout,
    const unsigned short* __restrict__ vproj, float* __restrict__ out) {
  __shared__ unsigned short qs[BQ][264];    // Q (bf16); reused as mid (bf16)
  __shared__ unsigned short offb[BQ][256];  // offsets, bf16
  __shared__ float awb[BQ][128];            // attn logits -> weights, f32
  __shared__ short idxs[4][128][4];         // 4-slot sample params (2q/epoch)
  __shared__ float wls[4][128][4];

  const int t = threadIdx.x;
  const int qg0 = blockIdx.x * BQ;
  const int n = qg0 / LQ_;

  {  // stage Q -> bf16 LDS
    const int c2 = (t & 127) * 2;
    const int rb = t >> 7;
#pragma unroll
    for (int i = 0; i < 8; ++i) {
      int rr = rb + i * 2;
      float2 v = *(const float2*)(query + (size_t)(qg0 + rr) * D_ + c2);
      *(unsigned int*)&qs[rr][c2] = (unsigned int)f2bf(v.x) | ((unsigned int)f2bf(v.y) << 16);
    }
  }
  __syncthreads();

  const int wave = t >> 6, lane = t & 63;
  const int arow = lane & 15;
  const int kg = (lane >> 4) * 8;
  const int row0 = (lane >> 4) * 4;

  {  // off+att GEMM: [16x256] @ [256x384], wave covers 6 col-tiles
    floatx4 acc[6] = {};
    for (int kk = 0; kk < 8; ++kk) {
      const int k0 = kk * 32;
      short8 af = *(const short8*)&qs[arow][k0 + kg];
#pragma unroll
      for (int i = 0; i < 6; ++i) {
        const int col = wave * 96 + i * 16 + (lane & 15);
        const unsigned short* bp = (col < 256) ? (wt + col * 256)
                                               : (wt + 65536 + (col - 256) * 256);
        short8 bf = *(const short8*)(bp + k0 + kg);
        acc[i] = __builtin_amdgcn_mfma_f32_16x16x32_bf16(af, bf, acc[i], 0, 0, 0);
      }
    }
#pragma unroll
    for (int i = 0; i < 6; ++i) {
      const int col = wave * 96 + i * 16 + (lane & 15);
      if (col < 256) {
        const float bb = boff[col];
#pragma unroll
        for (int j = 0; j < 4; ++j) offb[row0 + j][col] = f2bf(acc[i][j] + bb);
      } else {
        const float bb = batt[col - 256];
#pragma unroll
        for (int j = 0; j < 4; ++j) awb[row0 + j][col - 256] = acc[i][j] + bb;
      }
    }
  }
  __syncthreads();

  if (t < 128) {  // softmax over 16 per (q, m): q = t>>3, m = t&7
    const int q = t >> 3, m = t & 7;
    float v[16]; float mx = -1e30f;
#pragma unroll
    for (int s = 0; s < 16; ++s) { v[s] = awb[q][m * 16 + s]; mx = fmaxf(mx, v[s]); }
    float sum = 0.f;
#pragma unroll
    for (int s = 0; s < 16; ++s) { v[s] = __expf(v[s] - mx); sum += v[s]; }
    const float inv = 1.f / sum;
#pragma unroll
    for (int s = 0; s < 16; ++s) awb[q][m * 16 + s] = v[s] * inv;
  }
  __syncthreads();

  // sampling: 8 epochs x 2 queries, one barrier per epoch.
  // Slot safety: setup(e) writes slots {0,1} or {2,3}; gather(e-1) reads the
  // other pair; barrier(e) orders gather(e-1) before setup(e+1).
  const int sid = t & 127;           // sample id for setup
  const int qh  = t >> 7;            // which of the 2 queries this thread sets up
  const int m_g = t >> 5;
  const int g = t & 31;
  const int p8 = g >> 3;             // corner 0..3
  const int d4 = (g & 7) * 4;        // 4 bf16 per lane
  const unsigned short* vbase = vproj + ((size_t)(n * M_ + m_g) * LEN_) * DH_ + d4;

  for (int e = 0; e < 8; ++e) {
    const int qp = 2 * e + qh;
    const int slot = qp & 3;
    {
      const int l = (sid >> 2) & 3;
      const int Wl = c_HW[l];
      const int st = c_start[l];
      const float rx = refp[(((size_t)(qg0 + qp)) * L_ + l) * 2 + 0];
      const float ry = refp[(((size_t)(qg0 + qp)) * L_ + l) * 2 + 1];
      const float gx = rx * (float)Wl + bf2f(offb[qp][2 * sid])     - 0.5f;
      const float gy = ry * (float)Wl + bf2f(offb[qp][2 * sid + 1]) - 0.5f;
      const float fx0 = floorf(gx), fy0 = floorf(gy);
      const int x0 = (int)fx0, y0 = (int)fy0;
      const float wx1 = gx - fx0, wy1 = gy - fy0;
      const float wx0 = 1.f - wx1, wy0 = 1.f - wy1;
      const float a = awb[qp][sid];
      const bool vx0 = (x0 >= 0) && (x0 < Wl);
      const bool vx1 = (x0 + 1 >= 0) && (x0 + 1 < Wl);
      const bool vy0 = (y0 >= 0) && (y0 < Wl);
      const bool vy1 = (y0 + 1 >= 0) && (y0 + 1 < Wl);
      idxs[slot][sid][0] = (short)((vx0 && vy0) ? st + y0 * Wl + x0 : -1);
      idxs[slot][sid][1] = (short)((vx1 && vy0) ? st + y0 * Wl + x0 + 1 : -1);
      idxs[slot][sid][2] = (short)((vx0 && vy1) ? st + (y0 + 1) * Wl + x0 : -1);
      idxs[slot][sid][3] = (short)((vx1 && vy1) ? st + (y0 + 1) * Wl + x0 + 1 : -1);
      wls[slot][sid][0] = wy0 * wx0 * a;
      wls[slot][sid][1] = wy0 * wx1 * a;
      wls[slot][sid][2] = wy1 * wx0 * a;
      wls[slot][sid][3] = wy1 * wx1 * a;
    }
    __syncthreads();

    const int sl0 = (2 * e) & 3, sl1 = sl0 + 1;
    const int sidb = m_g * 16;
    float a0 = 0.f, a1 = 0.f, a2 = 0.f, a3 = 0.f;
    float b0 = 0.f, b1 = 0.f, b2 = 0.f, b3 = 0.f;
#pragma unroll
    for (int s = 0; s < 16; ++s) {
      const int ix = (int)idxs[sl0][sidb + s][p8];
      const int ixc = (ix >= 0) ? ix : 0;
      const float wv = (ix >= 0) ? wls[sl0][sidb + s][p8] : 0.f;
      const unsigned short* p = vbase + (size_t)ixc * DH_;
      const uint2 u = *(const uint2*)p;
      a0 += __builtin_bit_cast(float, u.x << 16) * wv;
      a1 += __builtin_bit_cast(float, u.x & 0xffff0000u) * wv;
      a2 += __builtin_bit_cast(float, u.y << 16) * wv;
      a3 += __builtin_bit_cast(float, u.y & 0xffff0000u) * wv;
    }
#pragma unroll
    for (int s = 0; s < 16; ++s) {
      const int ix = (int)idxs[sl1][sidb + s][p8];
      const int ixc = (ix >= 0) ? ix : 0;
      const float wv = (ix >= 0) ? wls[sl1][sidb + s][p8] : 0.f;
      const unsigned short* p = vbase + (size_t)ixc * DH_;
      const uint2 u = *(const uint2*)p;
      b0 += __builtin_bit_cast(float, u.x << 16) * wv;
      b1 += __builtin_bit_cast(float, u.x & 0xffff0000u) * wv;
      b2 += __builtin_bit_cast(float, u.y << 16) * wv;
      b3 += __builtin_bit_cast(float, u.y & 0xffff0000u) * wv;
    }
    a0 += __shfl_xor(a0, 8);  a1 += __shfl_xor(a1, 8);
    a2 += __shfl_xor(a2, 8);  a3 += __shfl_xor(a3, 8);
    a0 += __shfl_xor(a0, 16); a1 += __shfl_xor(a1, 16);
    a2 += __shfl_xor(a2, 16); a3 += __shfl_xor(a3, 16);
    b0 += __shfl_xor(b0, 8);  b1 += __shfl_xor(b1, 8);
    b2 += __shfl_xor(b2, 8);  b3 += __shfl_xor(b3, 8);
    b0 += __shfl_xor(b0, 16); b1 += __shfl_xor(b1, 16);
    b2 += __shfl_xor(b2, 16); b3 += __shfl_xor(b3, 16);
    if (g < 8) {
      unsigned int* mp0 = (unsigned int*)&qs[2 * e][m_g * 32 + d4];
      mp0[0] = (unsigned int)f2bf(a0) | ((unsigned int)f2bf(a1) << 16);
      mp0[1] = (unsigned int)f2bf(a2) | ((unsigned int)f2bf(a3) << 16);
      unsigned int* mp1 = (unsigned int*)&qs[2 * e + 1][m_g * 32 + d4];
      mp1[0] = (unsigned int)f2bf(b0) | ((unsigned int)f2bf(b1) << 16);
      mp1[1] = (unsigned int)f2bf(b2) | ((unsigned int)f2bf(b3) << 16);
    }
  }
  __syncthreads();

  {  // out GEMM: mid [16x256] @ Wout [256x256], wave covers 4 col-tiles
    floatx4 acc[4] = {};
    for (int kk = 0; kk < 8; ++kk) {
      const int k0 = kk * 32;
      short8 af = *(const short8*)&qs[arow][k0 + kg];
#pragma unroll
      for (int i = 0; i < 4; ++i) {
        const int col = wave * 64 + i * 16 + (lane & 15);
        short8 bf = *(const short8*)(wt + 98304 + col * 256 + k0 + kg);
        acc[i] = __builtin_amdgcn_mfma_f32_16x16x32_bf16(af, bf, acc[i], 0, 0, 0);
      }
    }
#pragma unroll
    for (int i = 0; i < 4; ++i) {
      const int col = wave * 64 + i * 16 + (lane & 15);
      const float bb = bout[col];
#pragma unroll
      for (int j = 0; j < 4; ++j)
        out[(size_t)(qg0 + row0 + j) * D_ + col] = acc[i][j] + bb;
    }
  }
}

extern "C" void kernel_launch(void* const* d_in, const int* in_sizes, int n_in,
                              void* d_out, int out_size, void* d_ws, size_t ws_size,
                              hipStream_t stream) {
  const float* query = (const float*)d_in[0];
  const float* refp  = (const float*)d_in[1];
  const float* value = (const float*)d_in[2];
  const float* Wv    = (const float*)d_in[4];
  const float* bv    = (const float*)d_in[5];
  const float* Woff  = (const float*)d_in[6];
  const float* boff  = (const float*)d_in[7];
  const float* Watt  = (const float*)d_in[8];
  const float* batt  = (const float*)d_in[9];
  const float* Wout  = (const float*)d_in[10];
  const float* bout  = (const float*)d_in[11];
  float* out = (float*)d_out;

  unsigned short* vproj = (unsigned short*)d_ws;
  unsigned short* wt    = (unsigned short*)((char*)d_ws + WT_BYTE_OFF);
  const unsigned short* Wvt = wt + 163840;

  dim3 blk(256);
  hipLaunchKernelGGL(prep_kernel, dim3(896), blk, 0, stream, Woff, Watt, Wout, Wv, wt);
  hipLaunchKernelGGL(vproj_kernel, dim3((N_ * LEN_) / 64), blk, 0, stream, value, Wvt, bv, vproj);
  hipLaunchKernelGGL(msda_kernel, dim3((N_ * LQ_) / BQ), blk, 0, stream,
                     query, refp, wt, boff, batt, bout, vproj, out);
}

// Round 8
// 265.934 us; speedup vs baseline: 1.1799x; 1.1799x over previous
//
#include <hip/hip_runtime.h>

typedef __attribute__((ext_vector_type(8))) short short8;
typedef __attribute__((ext_vector_type(4))) float floatx4;

#define N_    2
#define LQ_   21760
#define D_    256
#define M_    8
#define L_    4
#define P_    4
#define DH_   32
#define LEN_  21760
#define BQ    16

__constant__ int c_start[4] = {0, 16384, 20480, 21504};
__constant__ int c_HW[4]    = {128, 64, 32, 16};

// ws layout (bytes):
//   vproj bf16 [N*M][LEN_][32] @ 0  (22,282,240 B)
//   wt bf16: Wofft[256][256] @ elem 0, Wattt[128][256] @ 65536,
//            Woutt[256][256] @ 98304, Wvt[256][256] @ 163840
#define WT_BYTE_OFF 22282240u

__device__ __forceinline__ unsigned short f2bf(float f) {
  unsigned int u = __builtin_bit_cast(unsigned int, f);
  u += 0x7fffu + ((u >> 16) & 1u);   // RNE
  return (unsigned short)(u >> 16);
}
__device__ __forceinline__ float bf2f(unsigned short s) {
  return __builtin_bit_cast(float, ((unsigned int)s) << 16);
}

// ---------------- prep: transpose + convert weights to bf16 ----------------
__global__ __launch_bounds__(256) void prep_kernel(
    const float* __restrict__ Woff, const float* __restrict__ Watt,
    const float* __restrict__ Wout, const float* __restrict__ Wv,
    unsigned short* __restrict__ wt) {
  const int b = blockIdx.x, t = threadIdx.x;
  const float* src; int ncols, n; unsigned short* dst;
  if (b < 256)      { src = Woff; ncols = 256; n = b;       dst = wt + 0      + n * 256; }
  else if (b < 384) { src = Watt; ncols = 128; n = b - 256; dst = wt + 65536  + n * 256; }
  else if (b < 640) { src = Wout; ncols = 256; n = b - 384; dst = wt + 98304  + n * 256; }
  else              { src = Wv;   ncols = 256; n = b - 640; dst = wt + 163840 + n * 256; }
  dst[t] = f2bf(src[(size_t)t * ncols + n]);
}

// ---------------- vproj: value @ W_val + b_val -> bf16 [n][m][pix][32] -----
__global__ __launch_bounds__(256, 2) void vproj_kernel(
    const float* __restrict__ value, const unsigned short* __restrict__ Wvt,
    const float* __restrict__ bv, unsigned short* __restrict__ vout) {
  __shared__ unsigned short vs[64][264];
  const int t = threadIdx.x;
  const int r0 = blockIdx.x * 64;
  {
    const int c2 = (t & 127) * 2;
    const int rb = t >> 7;
#pragma unroll
    for (int i = 0; i < 32; ++i) {
      int rr = rb + i * 2;
      float2 v = *(const float2*)(value + (size_t)(r0 + rr) * D_ + c2);
      *(unsigned int*)&vs[rr][c2] = (unsigned int)f2bf(v.x) | ((unsigned int)f2bf(v.y) << 16);
    }
  }
  __syncthreads();
  const int wave = t >> 6, lane = t & 63;
  const int arow = wave * 16 + (lane & 15);
  const int kg = (lane >> 4) * 8;
  floatx4 acc[16] = {};
  for (int kk = 0; kk < 8; ++kk) {
    const int k0 = kk * 32;
    short8 af = *(const short8*)&vs[arow][k0 + kg];
#pragma unroll
    for (int ct = 0; ct < 16; ++ct) {
      const int col = ct * 16 + (lane & 15);
      short8 bf = *(const short8*)(Wvt + col * 256 + k0 + kg);
      acc[ct] = __builtin_amdgcn_mfma_f32_16x16x32_bf16(af, bf, acc[ct], 0, 0, 0);
    }
  }
  const int n = (r0 >= LEN_) ? 1 : 0;
  const int pixbase = r0 - n * LEN_ + wave * 16 + ((lane >> 4) * 4);
#pragma unroll
  for (int ct = 0; ct < 16; ++ct) {
    const int gc = ct * 16 + (lane & 15);
    const int m = gc >> 5, d = gc & 31;
    const float bb = bv[gc];
    unsigned short* ob = vout + ((size_t)(n * M_ + m) * LEN_) * DH_ + d;
#pragma unroll
    for (int j = 0; j < 4; ++j)
      ob[(size_t)(pixbase + j) * DH_] = f2bf(acc[ct][j] + bb);
  }
}

// ---------------- msda: fused proj/softmax/sample/out ----------------------
__global__ __launch_bounds__(256, 5) void msda_kernel(
    const float* __restrict__ query, const float* __restrict__ refp,
    const unsigned short* __restrict__ wt,
    const float* __restrict__ boff, const float* __restrict__ batt,
    const float* __restrict__ bout,
    const unsigned short* __restrict__ vproj, float* __restrict__ out) {
  __shared__ unsigned short qs[BQ][264];    // Q (bf16); reused as mid (bf16)
  __shared__ unsigned short offb[BQ][256];  // offsets, bf16
  __shared__ float awb[BQ][128];            // attn logits -> weights, f32
  __shared__ short idxs[2][128][4];         // double-buffered sample params
  __shared__ float wls[2][128][4];

  const int t = threadIdx.x;
  const int qg0 = blockIdx.x * BQ;
  const int n = qg0 / LQ_;

  {  // stage Q -> bf16 LDS
    const int c2 = (t & 127) * 2;
    const int rb = t >> 7;
#pragma unroll
    for (int i = 0; i < 8; ++i) {
      int rr = rb + i * 2;
      float2 v = *(const float2*)(query + (size_t)(qg0 + rr) * D_ + c2);
      *(unsigned int*)&qs[rr][c2] = (unsigned int)f2bf(v.x) | ((unsigned int)f2bf(v.y) << 16);
    }
  }
  __syncthreads();

  const int wave = t >> 6, lane = t & 63;
  const int arow = lane & 15;
  const int kg = (lane >> 4) * 8;
  const int row0 = (lane >> 4) * 4;

  {  // off+att GEMM: [16x256] @ [256x384], wave covers 6 col-tiles
    floatx4 acc[6] = {};
    for (int kk = 0; kk < 8; ++kk) {
      const int k0 = kk * 32;
      short8 af = *(const short8*)&qs[arow][k0 + kg];
#pragma unroll
      for (int i = 0; i < 6; ++i) {
        const int col = wave * 96 + i * 16 + (lane & 15);
        const unsigned short* bp = (col < 256) ? (wt + col * 256)
                                               : (wt + 65536 + (col - 256) * 256);
        short8 bf = *(const short8*)(bp + k0 + kg);
        acc[i] = __builtin_amdgcn_mfma_f32_16x16x32_bf16(af, bf, acc[i], 0, 0, 0);
      }
    }
#pragma unroll
    for (int i = 0; i < 6; ++i) {
      const int col = wave * 96 + i * 16 + (lane & 15);
      if (col < 256) {
        const float bb = boff[col];
#pragma unroll
        for (int j = 0; j < 4; ++j) offb[row0 + j][col] = f2bf(acc[i][j] + bb);
      } else {
        const float bb = batt[col - 256];
#pragma unroll
        for (int j = 0; j < 4; ++j) awb[row0 + j][col - 256] = acc[i][j] + bb;
      }
    }
  }
  __syncthreads();

  if (t < 128) {  // softmax over 16 per (q, m): q = t>>3, m = t&7
    const int q = t >> 3, m = t & 7;
    float v[16]; float mx = -1e30f;
#pragma unroll
    for (int s = 0; s < 16; ++s) { v[s] = awb[q][m * 16 + s]; mx = fmaxf(mx, v[s]); }
    float sum = 0.f;
#pragma unroll
    for (int s = 0; s < 16; ++s) { v[s] = __expf(v[s] - mx); sum += v[s]; }
    const float inv = 1.f / sum;
#pragma unroll
    for (int s = 0; s < 16; ++s) awb[q][m * 16 + s] = v[s] * inv;
  }
  __syncthreads();

  // sampling: single barrier per q (double-buffered params).
  // Safety: setup(q+2) rewriting slot[q&1] is ordered after barrier(q+1),
  // which every thread reaches only after finishing gather(q).
  const int m_g = t >> 5;
  const int g = t & 31;
  const int p8 = g >> 3;             // corner 0..3
  const int d4 = (g & 7) * 4;        // 4 bf16 per lane
  const unsigned short* vbase = vproj + ((size_t)(n * M_ + m_g) * LEN_) * DH_ + d4;

  for (int q = 0; q < BQ; ++q) {
    const int slot = q & 1;
    if (t < 128) {
      const int l = (t >> 2) & 3;
      const int Wl = c_HW[l];
      const int st = c_start[l];
      const float rx = refp[(((size_t)(qg0 + q)) * L_ + l) * 2 + 0];
      const float ry = refp[(((size_t)(qg0 + q)) * L_ + l) * 2 + 1];
      const float gx = rx * (float)Wl + bf2f(offb[q][2 * t])     - 0.5f;
      const float gy = ry * (float)Wl + bf2f(offb[q][2 * t + 1]) - 0.5f;
      const float fx0 = floorf(gx), fy0 = floorf(gy);
      const int x0 = (int)fx0, y0 = (int)fy0;
      const float wx1 = gx - fx0, wy1 = gy - fy0;
      const float wx0 = 1.f - wx1, wy0 = 1.f - wy1;
      const float a = awb[q][t];
      const bool vx0 = (x0 >= 0) && (x0 < Wl);
      const bool vx1 = (x0 + 1 >= 0) && (x0 + 1 < Wl);
      const bool vy0 = (y0 >= 0) && (y0 < Wl);
      const bool vy1 = (y0 + 1 >= 0) && (y0 + 1 < Wl);
      idxs[slot][t][0] = (short)((vx0 && vy0) ? st + y0 * Wl + x0 : -1);
      idxs[slot][t][1] = (short)((vx1 && vy0) ? st + y0 * Wl + x0 + 1 : -1);
      idxs[slot][t][2] = (short)((vx0 && vy1) ? st + (y0 + 1) * Wl + x0 : -1);
      idxs[slot][t][3] = (short)((vx1 && vy1) ? st + (y0 + 1) * Wl + x0 + 1 : -1);
      wls[slot][t][0] = wy0 * wx0 * a;
      wls[slot][t][1] = wy0 * wx1 * a;
      wls[slot][t][2] = wy1 * wx0 * a;
      wls[slot][t][3] = wy1 * wx1 * a;
    }
    __syncthreads();

    float a0 = 0.f, a1 = 0.f, a2 = 0.f, a3 = 0.f;
    const int sidb = m_g * 16;
#pragma unroll
    for (int s = 0; s < 16; ++s) {
      const int ix = (int)idxs[slot][sidb + s][p8];
      const int ixc = (ix >= 0) ? ix : 0;
      const float wv = (ix >= 0) ? wls[slot][sidb + s][p8] : 0.f;
      const unsigned short* p = vbase + (size_t)ixc * DH_;
      const uint2 u = *(const uint2*)p;
      a0 += __builtin_bit_cast(float, u.x << 16) * wv;
      a1 += __builtin_bit_cast(float, u.x & 0xffff0000u) * wv;
      a2 += __builtin_bit_cast(float, u.y << 16) * wv;
      a3 += __builtin_bit_cast(float, u.y & 0xffff0000u) * wv;
    }
    a0 += __shfl_xor(a0, 8);  a1 += __shfl_xor(a1, 8);
    a2 += __shfl_xor(a2, 8);  a3 += __shfl_xor(a3, 8);
    a0 += __shfl_xor(a0, 16); a1 += __shfl_xor(a1, 16);
    a2 += __shfl_xor(a2, 16); a3 += __shfl_xor(a3, 16);
    if (g < 8) {
      unsigned int* mp = (unsigned int*)&qs[q][m_g * 32 + d4];
      mp[0] = (unsigned int)f2bf(a0) | ((unsigned int)f2bf(a1) << 16);
      mp[1] = (unsigned int)f2bf(a2) | ((unsigned int)f2bf(a3) << 16);
    }
  }
  __syncthreads();

  {  // out GEMM: mid [16x256] @ Wout [256x256], wave covers 4 col-tiles
    floatx4 acc[4] = {};
    for (int kk = 0; kk < 8; ++kk) {
      const int k0 = kk * 32;
      short8 af = *(const short8*)&qs[arow][k0 + kg];
#pragma unroll
      for (int i = 0; i < 4; ++i) {
        const int col = wave * 64 + i * 16 + (lane & 15);
        short8 bf = *(const short8*)(wt + 98304 + col * 256 + k0 + kg);
        acc[i] = __builtin_amdgcn_mfma_f32_16x16x32_bf16(af, bf, acc[i], 0, 0, 0);
      }
    }
#pragma unroll
    for (int i = 0; i < 4; ++i) {
      const int col = wave * 64 + i * 16 + (lane & 15);
      const float bb = bout[col];
#pragma unroll
      for (int j = 0; j < 4; ++j)
        out[(size_t)(qg0 + row0 + j) * D_ + col] = acc[i][j] + bb;
    }
  }
}

extern "C" void kernel_launch(void* const* d_in, const int* in_sizes, int n_in,
                              void* d_out, int out_size, void* d_ws, size_t ws_size,
                              hipStream_t stream) {
  const float* query = (const float*)d_in[0];
  const float* refp  = (const float*)d_in[1];
  const float* value = (const float*)d_in[2];
  const float* Wv    = (const float*)d_in[4];
  const float* bv    = (const float*)d_in[5];
  const float* Woff  = (const float*)d_in[6];
  const float* boff  = (const float*)d_in[7];
  const float* Watt  = (const float*)d_in[8];
  const float* batt  = (const float*)d_in[9];
  const float* Wout  = (const float*)d_in[10];
  const float* bout  = (const float*)d_in[11];
  float* out = (float*)d_out;

  unsigned short* vproj = (unsigned short*)d_ws;
  unsigned short* wt    = (unsigned short*)((char*)d_ws + WT_BYTE_OFF);
  const unsigned short* Wvt = wt + 163840;

  dim3 blk(256);
  hipLaunchKernelGGL(prep_kernel, dim3(896), blk, 0, stream, Woff, Watt, Wout, Wv, wt);
  hipLaunchKernelGGL(vproj_kernel, dim3((N_ * LEN_) / 64), blk, 0, stream, value, Wvt, bv, vproj);
  hipLaunchKernelGGL(msda_kernel, dim3((N_ * LQ_) / BQ), blk, 0, stream,
                     query, refp, wt, boff, batt, bout, vproj, out);
}

// Round 9
// 261.533 us; speedup vs baseline: 1.1998x; 1.0168x over previous
//
#include <hip/hip_runtime.h>

typedef __attribute__((ext_vector_type(8))) short short8;
typedef __attribute__((ext_vector_type(4))) float floatx4;

#define N_    2
#define LQ_   21760
#define D_    256
#define M_    8
#define L_    4
#define P_    4
#define DH_   32
#define LEN_  21760
#define BQ    16

__constant__ int c_start[4] = {0, 16384, 20480, 21504};
__constant__ int c_HW[4]    = {128, 64, 32, 16};

// ws layout (bytes):
//   vproj bf16 [N*M][LEN_][32] @ 0  (22,282,240 B)
//   wt bf16: Wofft[256][256] @ elem 0, Wattt[128][256] @ 65536,
//            Woutt[256][256] @ 98304, Wvt[256][256] @ 163840
#define WT_BYTE_OFF 22282240u

__device__ __forceinline__ unsigned short f2bf(float f) {
  unsigned int u = __builtin_bit_cast(unsigned int, f);
  u += 0x7fffu + ((u >> 16) & 1u);   // RNE
  return (unsigned short)(u >> 16);
}
__device__ __forceinline__ float bf2f(unsigned short s) {
  return __builtin_bit_cast(float, ((unsigned int)s) << 16);
}

// ---------------- prep: transpose + convert weights to bf16 ----------------
__global__ __launch_bounds__(256) void prep_kernel(
    const float* __restrict__ Woff, const float* __restrict__ Watt,
    const float* __restrict__ Wout, const float* __restrict__ Wv,
    unsigned short* __restrict__ wt) {
  const int b = blockIdx.x, t = threadIdx.x;
  const float* src; int ncols, n; unsigned short* dst;
  if (b < 256)      { src = Woff; ncols = 256; n = b;       dst = wt + 0      + n * 256; }
  else if (b < 384) { src = Watt; ncols = 128; n = b - 256; dst = wt + 65536  + n * 256; }
  else if (b < 640) { src = Wout; ncols = 256; n = b - 384; dst = wt + 98304  + n * 256; }
  else              { src = Wv;   ncols = 256; n = b - 640; dst = wt + 163840 + n * 256; }
  dst[t] = f2bf(src[(size_t)t * ncols + n]);
}

// ---------------- vproj: value @ W_val + b_val -> bf16 [n][m][pix][32] -----
__global__ __launch_bounds__(256, 2) void vproj_kernel(
    const float* __restrict__ value, const unsigned short* __restrict__ Wvt,
    const float* __restrict__ bv, unsigned short* __restrict__ vout) {
  __shared__ unsigned short vs[64][264];
  const int t = threadIdx.x;
  const int r0 = blockIdx.x * 64;
  {
    const int c2 = (t & 127) * 2;
    const int rb = t >> 7;
#pragma unroll
    for (int i = 0; i < 32; ++i) {
      int rr = rb + i * 2;
      float2 v = *(const float2*)(value + (size_t)(r0 + rr) * D_ + c2);
      *(unsigned int*)&vs[rr][c2] = (unsigned int)f2bf(v.x) | ((unsigned int)f2bf(v.y) << 16);
    }
  }
  __syncthreads();
  const int wave = t >> 6, lane = t & 63;
  const int arow = wave * 16 + (lane & 15);
  const int kg = (lane >> 4) * 8;
  floatx4 acc[16] = {};
  for (int kk = 0; kk < 8; ++kk) {
    const int k0 = kk * 32;
    short8 af = *(const short8*)&vs[arow][k0 + kg];
#pragma unroll
    for (int ct = 0; ct < 16; ++ct) {
      const int col = ct * 16 + (lane & 15);
      short8 bf = *(const short8*)(Wvt + col * 256 + k0 + kg);
      acc[ct] = __builtin_amdgcn_mfma_f32_16x16x32_bf16(af, bf, acc[ct], 0, 0, 0);
    }
  }
  const int n = (r0 >= LEN_) ? 1 : 0;
  const int pixbase = r0 - n * LEN_ + wave * 16 + ((lane >> 4) * 4);
#pragma unroll
  for (int ct = 0; ct < 16; ++ct) {
    const int gc = ct * 16 + (lane & 15);
    const int m = gc >> 5, d = gc & 31;
    const float bb = bv[gc];
    unsigned short* ob = vout + ((size_t)(n * M_ + m) * LEN_) * DH_ + d;
#pragma unroll
    for (int j = 0; j < 4; ++j)
      ob[(size_t)(pixbase + j) * DH_] = f2bf(acc[ct][j] + bb);
  }
}

// ---------------- msda: fused proj/softmax/sample/out ----------------------
__global__ __launch_bounds__(256, 5) void msda_kernel(
    const float* __restrict__ query, const float* __restrict__ refp,
    const unsigned short* __restrict__ wt,
    const float* __restrict__ boff, const float* __restrict__ batt,
    const float* __restrict__ bout,
    const unsigned short* __restrict__ vproj, float* __restrict__ out) {
  __shared__ unsigned short qs[BQ][264];    // Q (bf16); reused as mid (bf16)
  __shared__ unsigned short offb[BQ][256];  // offsets, bf16
  __shared__ float awb[BQ][128];            // attn logits -> weights, f32
  __shared__ short idxs2[2][128];           // row0 base index (may be <0 / OOB; w=0 covers)
  __shared__ float wls2[2][128][4];         // [row*2+corner] weights, zeroed by validity

  const int t = threadIdx.x;
  // XCD-chunked swizzle: 2720 blocks = 8 XCDs x 340; each XCD serves one n.
  const int lb = (blockIdx.x & 7) * 340 + (blockIdx.x >> 3);
  const int qg0 = lb * BQ;
  const int n = qg0 / LQ_;

  {  // stage Q -> bf16 LDS
    const int c2 = (t & 127) * 2;
    const int rb = t >> 7;
#pragma unroll
    for (int i = 0; i < 8; ++i) {
      int rr = rb + i * 2;
      float2 v = *(const float2*)(query + (size_t)(qg0 + rr) * D_ + c2);
      *(unsigned int*)&qs[rr][c2] = (unsigned int)f2bf(v.x) | ((unsigned int)f2bf(v.y) << 16);
    }
  }
  __syncthreads();

  const int wave = t >> 6, lane = t & 63;
  const int arow = lane & 15;
  const int kg = (lane >> 4) * 8;
  const int row0 = (lane >> 4) * 4;

  {  // off+att GEMM: [16x256] @ [256x384], wave covers 6 col-tiles
    floatx4 acc[6] = {};
    for (int kk = 0; kk < 8; ++kk) {
      const int k0 = kk * 32;
      short8 af = *(const short8*)&qs[arow][k0 + kg];
#pragma unroll
      for (int i = 0; i < 6; ++i) {
        const int col = wave * 96 + i * 16 + (lane & 15);
        const unsigned short* bp = (col < 256) ? (wt + col * 256)
                                               : (wt + 65536 + (col - 256) * 256);
        short8 bf = *(const short8*)(bp + k0 + kg);
        acc[i] = __builtin_amdgcn_mfma_f32_16x16x32_bf16(af, bf, acc[i], 0, 0, 0);
      }
    }
#pragma unroll
    for (int i = 0; i < 6; ++i) {
      const int col = wave * 96 + i * 16 + (lane & 15);
      if (col < 256) {
        const float bb = boff[col];
#pragma unroll
        for (int j = 0; j < 4; ++j) offb[row0 + j][col] = f2bf(acc[i][j] + bb);
      } else {
        const float bb = batt[col - 256];
#pragma unroll
        for (int j = 0; j < 4; ++j) awb[row0 + j][col - 256] = acc[i][j] + bb;
      }
    }
  }
  __syncthreads();

  if (t < 128) {  // softmax over 16 per (q, m): q = t>>3, m = t&7
    const int q = t >> 3, m = t & 7;
    float v[16]; float mx = -1e30f;
#pragma unroll
    for (int s = 0; s < 16; ++s) { v[s] = awb[q][m * 16 + s]; mx = fmaxf(mx, v[s]); }
    float sum = 0.f;
#pragma unroll
    for (int s = 0; s < 16; ++s) { v[s] = __expf(v[s] - mx); sum += v[s]; }
    const float inv = 1.f / sum;
#pragma unroll
    for (int s = 0; s < 16; ++s) awb[q][m * 16 + s] = v[s] * inv;
  }
  __syncthreads();

  // sampling: single barrier per q (double-buffered params).
  // Lane layout per 32-lane head-group: bit4=row (y0/y1), bit3=corner (x0/x0+1),
  // bits0-2=d-quad. One uint2 load per lane per sample covers the sample's
  // 2x128B row-spans across the group (half the requests of 4x64B corners).
  const int m_g = t >> 5;
  const int g = t & 31;
  const bool rowhi = (g & 16) != 0;
  const int wsel = (g >> 3) & 3;           // row*2 + corner
  const int inrow = (g & 15) * 8;          // byte offset within 128B span
  const int d4 = (g & 7) * 4;
  const char* vbyte = (const char*)vproj + (size_t)(n * M_ + m_g) * LEN_ * DH_ * 2;

  constexpr int kHW[4] = {128, 64, 32, 16};

  for (int q = 0; q < BQ; ++q) {
    const int slot = q & 1;
    if (t < 128) {
      const int l = (t >> 2) & 3;
      const int Wl = c_HW[l];
      const int st = c_start[l];
      const float rx = refp[(((size_t)(qg0 + q)) * L_ + l) * 2 + 0];
      const float ry = refp[(((size_t)(qg0 + q)) * L_ + l) * 2 + 1];
      const float gx = rx * (float)Wl + bf2f(offb[q][2 * t])     - 0.5f;
      const float gy = ry * (float)Wl + bf2f(offb[q][2 * t + 1]) - 0.5f;
      const float fx0 = floorf(gx), fy0 = floorf(gy);
      const int x0 = (int)fx0, y0 = (int)fy0;
      const float wx1 = gx - fx0, wy1 = gy - fy0;
      const float wx0 = 1.f - wx1, wy0 = 1.f - wy1;
      const float a = awb[q][t];
      const bool vx0 = (x0 >= 0) && (x0 < Wl);
      const bool vx1 = (x0 + 1 >= 0) && (x0 + 1 < Wl);
      const bool vy0 = (y0 >= 0) && (y0 < Wl);
      const bool vy1 = (y0 + 1 >= 0) && (y0 + 1 < Wl);
      idxs2[slot][t] = (short)(st + y0 * Wl + x0);
      wls2[slot][t][0] = (vy0 && vx0) ? wy0 * wx0 * a : 0.f;
      wls2[slot][t][1] = (vy0 && vx1) ? wy0 * wx1 * a : 0.f;
      wls2[slot][t][2] = (vy1 && vx0) ? wy1 * wx0 * a : 0.f;
      wls2[slot][t][3] = (vy1 && vx1) ? wy1 * wx1 * a : 0.f;
    }
    __syncthreads();

    float a0 = 0.f, a1 = 0.f, a2 = 0.f, a3 = 0.f;
    const int sidb = m_g * 16;
#pragma unroll
    for (int s = 0; s < 16; ++s) {
      const int Wl_c = kHW[(s >> 2) & 3];
      const int rb = (int)idxs2[slot][sidb + s] + (rowhi ? Wl_c : 0);
      const float wv = wls2[slot][sidb + s][wsel];
      int ofs = rb * 64 + inrow;           // bytes within head slab
      ofs = (ofs > 0) ? ofs : 0;           // OOB-safe: garbage (finite) x w=0
      const uint2 u = *(const uint2*)(vbyte + ofs);
      a0 += __builtin_bit_cast(float, u.x << 16) * wv;
      a1 += __builtin_bit_cast(float, u.x & 0xffff0000u) * wv;
      a2 += __builtin_bit_cast(float, u.y << 16) * wv;
      a3 += __builtin_bit_cast(float, u.y & 0xffff0000u) * wv;
    }
    a0 += __shfl_xor(a0, 8);  a1 += __shfl_xor(a1, 8);
    a2 += __shfl_xor(a2, 8);  a3 += __shfl_xor(a3, 8);
    a0 += __shfl_xor(a0, 16); a1 += __shfl_xor(a1, 16);
    a2 += __shfl_xor(a2, 16); a3 += __shfl_xor(a3, 16);
    if (g < 8) {
      unsigned int* mp = (unsigned int*)&qs[q][m_g * 32 + d4];
      mp[0] = (unsigned int)f2bf(a0) | ((unsigned int)f2bf(a1) << 16);
      mp[1] = (unsigned int)f2bf(a2) | ((unsigned int)f2bf(a3) << 16);
    }
    __syncthreads();
  }

  {  // out GEMM: mid [16x256] @ Wout [256x256], wave covers 4 col-tiles
    floatx4 acc[4] = {};
    for (int kk = 0; kk < 8; ++kk) {
      const int k0 = kk * 32;
      short8 af = *(const short8*)&qs[arow][k0 + kg];
#pragma unroll
      for (int i = 0; i < 4; ++i) {
        const int col = wave * 64 + i * 16 + (lane & 15);
        short8 bf = *(const short8*)(wt + 98304 + col * 256 + k0 + kg);
        acc[i] = __builtin_amdgcn_mfma_f32_16x16x32_bf16(af, bf, acc[i], 0, 0, 0);
      }
    }
#pragma unroll
    for (int i = 0; i < 4; ++i) {
      const int col = wave * 64 + i * 16 + (lane & 15);
      const float bb = bout[col];
#pragma unroll
      for (int j = 0; j < 4; ++j)
        out[(size_t)(qg0 + row0 + j) * D_ + col] = acc[i][j] + bb;
    }
  }
}

extern "C" void kernel_launch(void* const* d_in, const int* in_sizes, int n_in,
                              void* d_out, int out_size, void* d_ws, size_t ws_size,
                              hipStream_t stream) {
  const float* query = (const float*)d_in[0];
  const float* refp  = (const float*)d_in[1];
  const float* value = (const float*)d_in[2];
  const float* Wv    = (const float*)d_in[4];
  const float* bv    = (const float*)d_in[5];
  const float* Woff  = (const float*)d_in[6];
  const float* boff  = (const float*)d_in[7];
  const float* Watt  = (const float*)d_in[8];
  const float* batt  = (const float*)d_in[9];
  const float* Wout  = (const float*)d_in[10];
  const float* bout  = (const float*)d_in[11];
  float* out = (float*)d_out;

  unsigned short* vproj = (unsigned short*)d_ws;
  unsigned short* wt    = (unsigned short*)((char*)d_ws + WT_BYTE_OFF);
  const unsigned short* Wvt = wt + 163840;

  dim3 blk(256);
  hipLaunchKernelGGL(prep_kernel, dim3(896), blk, 0, stream, Woff, Watt, Wout, Wv, wt);
  hipLaunchKernelGGL(vproj_kernel, dim3((N_ * LEN_) / 64), blk, 0, stream, value, Wvt, bv, vproj);
  hipLaunchKernelGGL(msda_kernel, dim3((N_ * LQ_) / BQ), blk, 0, stream,
                     query, refp, wt, boff, batt, bout, vproj, out);
}

// Round 10
// 236.959 us; speedup vs baseline: 1.3242x; 1.1037x over previous
//
#include <hip/hip_runtime.h>

typedef __attribute__((ext_vector_type(8))) short short8;
typedef __attribute__((ext_vector_type(4))) float floatx4;

#define N_    2
#define LQ_   21760
#define D_    256
#define M_    8
#define L_    4
#define P_    4
#define DH_   32
#define LEN_  21760
#define BQ    16

__constant__ int c_start[4] = {0, 16384, 20480, 21504};
__constant__ int c_HW[4]    = {128, 64, 32, 16};

// ws layout (bytes):
//   vproj bf16 [N*M][LEN_][32] @ 0  (22,282,240 B)
//   wt bf16: Wofft[256][256] @ elem 0, Wattt[128][256] @ 65536,
//            Woutt[256][256] @ 98304, Wvt[256][256] @ 163840
#define WT_BYTE_OFF 22282240u

__device__ __forceinline__ unsigned short f2bf(float f) {
  unsigned int u = __builtin_bit_cast(unsigned int, f);
  u += 0x7fffu + ((u >> 16) & 1u);   // RNE
  return (unsigned short)(u >> 16);
}
__device__ __forceinline__ float bf2f(unsigned short s) {
  return __builtin_bit_cast(float, ((unsigned int)s) << 16);
}

// ---------------- prep: transpose + convert weights to bf16 ----------------
__global__ __launch_bounds__(256) void prep_kernel(
    const float* __restrict__ Woff, const float* __restrict__ Watt,
    const float* __restrict__ Wout, const float* __restrict__ Wv,
    unsigned short* __restrict__ wt) {
  const int b = blockIdx.x, t = threadIdx.x;
  const float* src; int ncols, n; unsigned short* dst;
  if (b < 256)      { src = Woff; ncols = 256; n = b;       dst = wt + 0      + n * 256; }
  else if (b < 384) { src = Watt; ncols = 128; n = b - 256; dst = wt + 65536  + n * 256; }
  else if (b < 640) { src = Wout; ncols = 256; n = b - 384; dst = wt + 98304  + n * 256; }
  else              { src = Wv;   ncols = 256; n = b - 640; dst = wt + 163840 + n * 256; }
  dst[t] = f2bf(src[(size_t)t * ncols + n]);
}

// ---------------- vproj: value @ W_val + b_val -> bf16 [n][m][pix][32] -----
__global__ __launch_bounds__(256, 2) void vproj_kernel(
    const float* __restrict__ value, const unsigned short* __restrict__ Wvt,
    const float* __restrict__ bv, unsigned short* __restrict__ vout) {
  __shared__ unsigned short vs[64][264];
  const int t = threadIdx.x;
  const int r0 = blockIdx.x * 64;
  {
    const int c2 = (t & 127) * 2;
    const int rb = t >> 7;
#pragma unroll
    for (int i = 0; i < 32; ++i) {
      int rr = rb + i * 2;
      float2 v = *(const float2*)(value + (size_t)(r0 + rr) * D_ + c2);
      *(unsigned int*)&vs[rr][c2] = (unsigned int)f2bf(v.x) | ((unsigned int)f2bf(v.y) << 16);
    }
  }
  __syncthreads();
  const int wave = t >> 6, lane = t & 63;
  const int arow = wave * 16 + (lane & 15);
  const int kg = (lane >> 4) * 8;
  floatx4 acc[16] = {};
  for (int kk = 0; kk < 8; ++kk) {
    const int k0 = kk * 32;
    short8 af = *(const short8*)&vs[arow][k0 + kg];
#pragma unroll
    for (int ct = 0; ct < 16; ++ct) {
      const int col = ct * 16 + (lane & 15);
      short8 bf = *(const short8*)(Wvt + col * 256 + k0 + kg);
      acc[ct] = __builtin_amdgcn_mfma_f32_16x16x32_bf16(af, bf, acc[ct], 0, 0, 0);
    }
  }
  const int n = (r0 >= LEN_) ? 1 : 0;
  const int pixbase = r0 - n * LEN_ + wave * 16 + ((lane >> 4) * 4);
#pragma unroll
  for (int ct = 0; ct < 16; ++ct) {
    const int gc = ct * 16 + (lane & 15);
    const int m = gc >> 5, d = gc & 31;
    const float bb = bv[gc];
    unsigned short* ob = vout + ((size_t)(n * M_ + m) * LEN_) * DH_ + d;
#pragma unroll
    for (int j = 0; j < 4; ++j)
      ob[(size_t)(pixbase + j) * DH_] = f2bf(acc[ct][j] + bb);
  }
}

// ---------------- msda: fused proj/softmax/sample/out ----------------------
__global__ __launch_bounds__(256, 5) void msda_kernel(
    const float* __restrict__ query, const float* __restrict__ refp,
    const unsigned short* __restrict__ wt,
    const float* __restrict__ boff, const float* __restrict__ batt,
    const float* __restrict__ bout,
    const unsigned short* __restrict__ vproj, float* __restrict__ out) {
  __shared__ unsigned short qs[BQ][264];    // Q (bf16); reused as mid (bf16)
  __shared__ unsigned short offb[BQ][256];  // offsets, bf16
  __shared__ float awb[BQ][128];            // attn logits -> weights, f32
  __shared__ short idxs2[2][128];           // row0 base pixel (may be <0/OOB; w=0 covers)
  __shared__ float wls2[2][128][4];         // [row*2+corner] weights, zeroed by validity

  const int t = threadIdx.x;
  // XCD-chunked swizzle: 2720 blocks = 8 XCDs x 340; each XCD serves one n.
  const int lb = (blockIdx.x & 7) * 340 + (blockIdx.x >> 3);
  const int qg0 = lb * BQ;
  const int n = qg0 / LQ_;

  {  // stage Q -> bf16 LDS
    const int c2 = (t & 127) * 2;
    const int rb = t >> 7;
#pragma unroll
    for (int i = 0; i < 8; ++i) {
      int rr = rb + i * 2;
      float2 v = *(const float2*)(query + (size_t)(qg0 + rr) * D_ + c2);
      *(unsigned int*)&qs[rr][c2] = (unsigned int)f2bf(v.x) | ((unsigned int)f2bf(v.y) << 16);
    }
  }
  __syncthreads();

  const int wave = t >> 6, lane = t & 63;
  const int arow = lane & 15;
  const int kg = (lane >> 4) * 8;
  const int row0 = (lane >> 4) * 4;

  {  // off+att GEMM: [16x256] @ [256x384], wave covers 6 col-tiles
    floatx4 acc[6] = {};
    for (int kk = 0; kk < 8; ++kk) {
      const int k0 = kk * 32;
      short8 af = *(const short8*)&qs[arow][k0 + kg];
#pragma unroll
      for (int i = 0; i < 6; ++i) {
        const int col = wave * 96 + i * 16 + (lane & 15);
        const unsigned short* bp = (col < 256) ? (wt + col * 256)
                                               : (wt + 65536 + (col - 256) * 256);
        short8 bf = *(const short8*)(bp + k0 + kg);
        acc[i] = __builtin_amdgcn_mfma_f32_16x16x32_bf16(af, bf, acc[i], 0, 0, 0);
      }
    }
#pragma unroll
    for (int i = 0; i < 6; ++i) {
      const int col = wave * 96 + i * 16 + (lane & 15);
      if (col < 256) {
        const float bb = boff[col];
#pragma unroll
        for (int j = 0; j < 4; ++j) offb[row0 + j][col] = f2bf(acc[i][j] + bb);
      } else {
        const float bb = batt[col - 256];
#pragma unroll
        for (int j = 0; j < 4; ++j) awb[row0 + j][col - 256] = acc[i][j] + bb;
      }
    }
  }
  __syncthreads();

  if (t < 128) {  // softmax over 16 per (q, m): q = t>>3, m = t&7
    const int q = t >> 3, m = t & 7;
    float v[16]; float mx = -1e30f;
#pragma unroll
    for (int s = 0; s < 16; ++s) { v[s] = awb[q][m * 16 + s]; mx = fmaxf(mx, v[s]); }
    float sum = 0.f;
#pragma unroll
    for (int s = 0; s < 16; ++s) { v[s] = __expf(v[s] - mx); sum += v[s]; }
    const float inv = 1.f / sum;
#pragma unroll
    for (int s = 0; s < 16; ++s) awb[q][m * 16 + s] = v[s] * inv;
  }
  __syncthreads();

  // sampling: single barrier per q (double-buffered params).
  // Lane layout per 32-lane head-group: bit4=sample-parity, bit3=row,
  // bit2=corner, bits0-1=d-oct. Each lane loads uint4 (16B): a sample is
  // 16 lanes x 16B; 2 samples/iter, 8 iters/epoch (half the addresses of R9).
  const int m_g = t >> 5;
  const int g = t & 31;
  const int sp   = g >> 4;                 // sample parity in pair
  const int rsel = (g >> 3) & 1;           // row
  const int csel = (g >> 2) & 1;           // corner
  const int wsel = (g >> 2) & 3;           // row*2+corner
  const int doct = g & 3;                  // which 8-d group
  const char* vbyte = (const char*)vproj + (size_t)(n * M_ + m_g) * LEN_ * DH_ * 2;

  constexpr int kHW[4] = {128, 64, 32, 16};

  for (int q = 0; q < BQ; ++q) {
    const int slot = q & 1;
    if (t < 128) {
      const int l = (t >> 2) & 3;
      const int Wl = c_HW[l];
      const int st = c_start[l];
      const float rx = refp[(((size_t)(qg0 + q)) * L_ + l) * 2 + 0];
      const float ry = refp[(((size_t)(qg0 + q)) * L_ + l) * 2 + 1];
      const float gx = rx * (float)Wl + bf2f(offb[q][2 * t])     - 0.5f;
      const float gy = ry * (float)Wl + bf2f(offb[q][2 * t + 1]) - 0.5f;
      const float fx0 = floorf(gx), fy0 = floorf(gy);
      const int x0 = (int)fx0, y0 = (int)fy0;
      const float wx1 = gx - fx0, wy1 = gy - fy0;
      const float wx0 = 1.f - wx1, wy0 = 1.f - wy1;
      const float a = awb[q][t];
      const bool vx0 = (x0 >= 0) && (x0 < Wl);
      const bool vx1 = (x0 + 1 >= 0) && (x0 + 1 < Wl);
      const bool vy0 = (y0 >= 0) && (y0 < Wl);
      const bool vy1 = (y0 + 1 >= 0) && (y0 + 1 < Wl);
      idxs2[slot][t] = (short)(st + y0 * Wl + x0);
      wls2[slot][t][0] = (vy0 && vx0) ? wy0 * wx0 * a : 0.f;
      wls2[slot][t][1] = (vy0 && vx1) ? wy0 * wx1 * a : 0.f;
      wls2[slot][t][2] = (vy1 && vx0) ? wy1 * wx0 * a : 0.f;
      wls2[slot][t][3] = (vy1 && vx1) ? wy1 * wx1 * a : 0.f;
    }
    __syncthreads();

    float acc[8] = {};
    const int sidb = m_g * 16;
#pragma unroll
    for (int i = 0; i < 8; ++i) {
      const int s = 2 * i + sp;
      const int Wl_c = kHW[(i >> 1) & 3];  // compile-time level per iter
      const int ix = (int)idxs2[slot][sidb + s];
      const float wv = wls2[slot][sidb + s][wsel];
      int ofs = (ix + rsel * Wl_c + csel) * 64 + doct * 16;
      ofs = (ofs > 0) ? ofs : 0;           // OOB-safe: finite garbage x w=0
      const uint4 u = *(const uint4*)(vbyte + ofs);
      acc[0] += __builtin_bit_cast(float, u.x << 16) * wv;
      acc[1] += __builtin_bit_cast(float, u.x & 0xffff0000u) * wv;
      acc[2] += __builtin_bit_cast(float, u.y << 16) * wv;
      acc[3] += __builtin_bit_cast(float, u.y & 0xffff0000u) * wv;
      acc[4] += __builtin_bit_cast(float, u.z << 16) * wv;
      acc[5] += __builtin_bit_cast(float, u.z & 0xffff0000u) * wv;
      acc[6] += __builtin_bit_cast(float, u.w << 16) * wv;
      acc[7] += __builtin_bit_cast(float, u.w & 0xffff0000u) * wv;
    }
#pragma unroll
    for (int k = 0; k < 8; ++k) {
      acc[k] += __shfl_xor(acc[k], 4);     // corner
      acc[k] += __shfl_xor(acc[k], 8);     // row
      acc[k] += __shfl_xor(acc[k], 16);    // sample parity
    }
    if (g < 4) {
      uint4 st4;
      st4.x = (unsigned int)f2bf(acc[0]) | ((unsigned int)f2bf(acc[1]) << 16);
      st4.y = (unsigned int)f2bf(acc[2]) | ((unsigned int)f2bf(acc[3]) << 16);
      st4.z = (unsigned int)f2bf(acc[4]) | ((unsigned int)f2bf(acc[5]) << 16);
      st4.w = (unsigned int)f2bf(acc[6]) | ((unsigned int)f2bf(acc[7]) << 16);
      *(uint4*)&qs[q][m_g * 32 + doct * 8] = st4;
    }
  }
  __syncthreads();

  {  // out GEMM: mid [16x256] @ Wout [256x256], wave covers 4 col-tiles
    floatx4 acc[4] = {};
    for (int kk = 0; kk < 8; ++kk) {
      const int k0 = kk * 32;
      short8 af = *(const short8*)&qs[arow][k0 + kg];
#pragma unroll
      for (int i = 0; i < 4; ++i) {
        const int col = wave * 64 + i * 16 + (lane & 15);
        short8 bf = *(const short8*)(wt + 98304 + col * 256 + k0 + kg);
        acc[i] = __builtin_amdgcn_mfma_f32_16x16x32_bf16(af, bf, acc[i], 0, 0, 0);
      }
    }
#pragma unroll
    for (int i = 0; i < 4; ++i) {
      const int col = wave * 64 + i * 16 + (lane & 15);
      const float bb = bout[col];
#pragma unroll
      for (int j = 0; j < 4; ++j)
        out[(size_t)(qg0 + row0 + j) * D_ + col] = acc[i][j] + bb;
    }
  }
}

extern "C" void kernel_launch(void* const* d_in, const int* in_sizes, int n_in,
                              void* d_out, int out_size, void* d_ws, size_t ws_size,
                              hipStream_t stream) {
  const float* query = (const float*)d_in[0];
  const float* refp  = (const float*)d_in[1];
  const float* value = (const float*)d_in[2];
  const float* Wv    = (const float*)d_in[4];
  const float* bv    = (const float*)d_in[5];
  const float* Woff  = (const float*)d_in[6];
  const float* boff  = (const float*)d_in[7];
  const float* Watt  = (const float*)d_in[8];
  const float* batt  = (const float*)d_in[9];
  const float* Wout  = (const float*)d_in[10];
  const float* bout  = (const float*)d_in[11];
  float* out = (float*)d_out;

  unsigned short* vproj = (unsigned short*)d_ws;
  unsigned short* wt    = (unsigned short*)((char*)d_ws + WT_BYTE_OFF);
  const unsigned short* Wvt = wt + 163840;

  dim3 blk(256);
  hipLaunchKernelGGL(prep_kernel, dim3(896), blk, 0, stream, Woff, Watt, Wout, Wv, wt);
  hipLaunchKernelGGL(vproj_kernel, dim3((N_ * LEN_) / 64), blk, 0, stream, value, Wvt, bv, vproj);
  hipLaunchKernelGGL(msda_kernel, dim3((N_ * LQ_) / BQ), blk, 0, stream,
                     query, refp, wt, boff, batt, bout, vproj, out);
}